// Round 3
// baseline (176.900 us; speedup 1.0000x reference)
//
#include <hip/hip_runtime.h>

// x shape (B, T, A, D) = (256, 2048, 22, 2) fp32
#define BB 256
#define TT 2048
#define AD 44               // A*D
#define AD4 11              // float4 chunks per (b,t) row
#define F4_PER_B (TT * AD4) // 22528 float4 per batch (divisible by 64 and 256)
#define NBLK (BB * F4_PER_B / 256)  // 22528 blocks

typedef float v4 __attribute__((ext_vector_type(4)));  // native vector: OK for nontemporal builtins

// Init atomic targets: mn = min NaN t, mxk = min over (4096 - t)  (i.e. max t).
__global__ __launch_bounds__(256) void init_minmax(unsigned* __restrict__ mn,
                                                   unsigned* __restrict__ mxk) {
  mn[threadIdx.x] = 0xFFFFFFFFu;
  mxk[threadIdx.x] = 0xFFFFFFFFu;
}

// Streaming copy x->out at full BW; NaN-range detection rides along.
// A wave (64 consecutive gid) never crosses a batch boundary (22528 % 64 == 0),
// and t is monotone nondecreasing in gid, so first/last NaN lane give the
// wave's min/max NaN t.
__global__ __launch_bounds__(256) void scan_copy(const v4* __restrict__ x4,
                                                 v4* __restrict__ out4,
                                                 unsigned* __restrict__ mn,
                                                 unsigned* __restrict__ mxk) {
  const int gid = blockIdx.x * 256 + threadIdx.x;
  const int b = gid / F4_PER_B;
  const int rem = gid - b * F4_PER_B;
  const int t = rem / AD4;

  const v4 v = x4[gid];
  __builtin_nontemporal_store(v, &out4[gid]);

  const bool n = (v.x != v.x) || (v.y != v.y) || (v.z != v.z) || (v.w != v.w);
  const unsigned long long m = __ballot(n);
  if (m != 0ull) {                       // wave-uniform branch; rare
    const int fl = __ffsll((unsigned long long)m) - 1;  // first NaN lane
    const int ll = 63 - __clzll((unsigned long long)m); // last NaN lane
    const int tmin = __shfl(t, fl);
    const int tmax = __shfl(t, ll);
    if ((threadIdx.x & 63) == 0) {       // b is wave-uniform
      atomicMin(&mn[b], (unsigned)tmin);
      atomicMin(&mxk[b], (unsigned)(4096 - tmax));
    }
  }
}

// Rewrite only the gap region with interpolated values.
__global__ __launch_bounds__(256) void fix_gap(const v4* __restrict__ x4,
                                               v4* __restrict__ out4,
                                               const unsigned* __restrict__ mn,
                                               const unsigned* __restrict__ mxk) {
  const int b = blockIdx.x;
  const int tid = threadIdx.x;
  const int s = (int)mn[b] - 1;                 // index before first NaN
  const int e = (4096 - (int)mxk[b]) + 1;       // index after last NaN

  __shared__ v4 sxs[AD4], sxe[AD4];
  const size_t base = (size_t)b * F4_PER_B;
  if (tid < AD4) sxs[tid] = x4[base + (size_t)s * AD4 + tid];
  if (tid >= 64 && tid < 64 + AD4) sxe[tid - 64] = x4[base + (size_t)e * AD4 + (tid - 64)];
  __syncthreads();

  const float inv = 1.0f / (float)(e - s);
  const int total = (e - s - 1) * AD4;          // float4s in the gap
  for (int i = tid; i < total; i += 256) {
    const int dt = i / AD4;                      // 0..glen-1
    const int c = i - dt * AD4;
    const int t = s + 1 + dt;
    const float w = (float)(dt + 1) * inv;       // (t - s)/(e - s)
    const float om = 1.0f - w;
    const v4 a = sxs[c];
    const v4 z = sxe[c];
    v4 r;
    r.x = a.x * om + z.x * w;
    r.y = a.y * om + z.y * w;
    r.z = a.z * om + z.z * w;
    r.w = a.w * om + z.w * w;
    __builtin_nontemporal_store(r, &out4[base + (size_t)t * AD4 + c]);
  }
}

extern "C" void kernel_launch(void* const* d_in, const int* in_sizes, int n_in,
                              void* d_out, int out_size, void* d_ws, size_t ws_size,
                              hipStream_t stream) {
  const v4* x4 = (const v4*)d_in[0];
  v4* out4 = (v4*)d_out;

  // ws layout: [0,1KB) mn (256 u32), [1KB,2KB) mxk (256 u32)
  unsigned* mn = (unsigned*)d_ws;
  unsigned* mxk = (unsigned*)((char*)d_ws + 1024);

  init_minmax<<<1, 256, 0, stream>>>(mn, mxk);
  scan_copy<<<NBLK, 256, 0, stream>>>(x4, out4, mn, mxk);
  fix_gap<<<BB, 256, 0, stream>>>(x4, out4, mn, mxk);
}

// Round 4
// 165.580 us; speedup vs baseline: 1.0684x; 1.0684x over previous
//
#include <hip/hip_runtime.h>

// x shape (B, T, A, D) = (256, 2048, 22, 2) fp32
#define BB 256
#define TT 2048
#define AD 44                 // A*D
#define AD4 11                // float4 chunks per (b,t) row
#define F4_PER_B (TT * AD4)   // 22528 float4 per batch
#define ELEMS 8               // float4 per thread
#define BLK_F4 (256 * ELEMS)  // 2048 float4 per block = F4_PER_B / 11
#define BLOCKS_PER_B 11
#define NBLK (BB * BLOCKS_PER_B)  // 2816 blocks

typedef float v4 __attribute__((ext_vector_type(4)));

// Streaming copy x->out with 8 float4/thread for MLP; NaN-range detection
// rides along. Each block covers 2048 consecutive float4 = 1/11 of a batch,
// so b is block-uniform.
__global__ __launch_bounds__(256) void scan_copy(const v4* __restrict__ x4,
                                                 v4* __restrict__ out4,
                                                 unsigned* __restrict__ mn,
                                                 unsigned* __restrict__ mxk) {
  const int tid = threadIdx.x;
  const int b = blockIdx.x / BLOCKS_PER_B;
  const int blk_in_b = blockIdx.x - b * BLOCKS_PER_B;
  const int base_in_b = blk_in_b * BLK_F4;          // float4 offset within batch
  const size_t base = (size_t)b * F4_PER_B + base_in_b;

  // Issue all 8 loads first (independent -> 8 outstanding vmem ops).
  v4 v[ELEMS];
#pragma unroll
  for (int k = 0; k < ELEMS; ++k) {
    v[k] = x4[base + k * 256 + tid];
  }

  int tmin = TT;
  int tmax = -1;
#pragma unroll
  for (int k = 0; k < ELEMS; ++k) {
    const int off = k * 256 + tid;
    out4[base + off] = v[k];
    const v4 w = v[k];
    const bool n = (w.x != w.x) || (w.y != w.y) || (w.z != w.z) || (w.w != w.w);
    if (n) {
      const int t = (base_in_b + off) / AD4;        // magic-mul const div
      tmin = min(tmin, t);
      tmax = max(tmax, t);
    }
  }

  const unsigned long long m = __ballot(tmax >= 0);
  if (m != 0ull) {                                  // wave-uniform, rare
#pragma unroll
    for (int d = 32; d > 0; d >>= 1) {
      tmin = min(tmin, __shfl_xor(tmin, d));
      tmax = max(tmax, __shfl_xor(tmax, d));
    }
    if ((tid & 63) == 0) {
      atomicMin(&mn[b], (unsigned)tmin);
      atomicMin(&mxk[b], (unsigned)(4096 - tmax));
    }
  }
}

// Rewrite only the gap region with interpolated values.
__global__ __launch_bounds__(256) void fix_gap(const v4* __restrict__ x4,
                                               v4* __restrict__ out4,
                                               const unsigned* __restrict__ mn,
                                               const unsigned* __restrict__ mxk) {
  const int b = blockIdx.x;
  const int tid = threadIdx.x;
  const int s = (int)mn[b] - 1;                 // index before first NaN
  const int e = (4096 - (int)mxk[b]) + 1;       // index after last NaN

  __shared__ v4 sxs[AD4], sxe[AD4];
  const size_t base = (size_t)b * F4_PER_B;
  if (tid < AD4) sxs[tid] = x4[base + (size_t)s * AD4 + tid];
  if (tid >= 64 && tid < 64 + AD4) sxe[tid - 64] = x4[base + (size_t)e * AD4 + (tid - 64)];
  __syncthreads();

  const float inv = 1.0f / (float)(e - s);
  const int total = (e - s - 1) * AD4;          // float4s in the gap
  for (int i = tid; i < total; i += 256) {
    const int dt = i / AD4;
    const int c = i - dt * AD4;
    const int t = s + 1 + dt;
    const float w = (float)(dt + 1) * inv;      // (t - s)/(e - s)
    const float om = 1.0f - w;
    const v4 a = sxs[c];
    const v4 z = sxe[c];
    v4 r;
    r.x = a.x * om + z.x * w;
    r.y = a.y * om + z.y * w;
    r.z = a.z * om + z.z * w;
    r.w = a.w * om + z.w * w;
    out4[base + (size_t)t * AD4 + c] = r;
  }
}

extern "C" void kernel_launch(void* const* d_in, const int* in_sizes, int n_in,
                              void* d_out, int out_size, void* d_ws, size_t ws_size,
                              hipStream_t stream) {
  const v4* x4 = (const v4*)d_in[0];
  v4* out4 = (v4*)d_out;

  // ws layout: [0,1KB) mn (256 u32), [1KB,2KB) mxk (256 u32)
  unsigned* mn = (unsigned*)d_ws;
  unsigned* mxk = (unsigned*)((char*)d_ws + 1024);

  // 0xFF bytes == 0xFFFFFFFF words: init for both atomicMin targets.
  hipMemsetAsync(d_ws, 0xFF, 2048, stream);

  scan_copy<<<NBLK, 256, 0, stream>>>(x4, out4, mn, mxk);
  fix_gap<<<BB, 256, 0, stream>>>(x4, out4, mn, mxk);
}